// Round 9
// baseline (142.920 us; speedup 1.0000x reference)
//
#include <hip/hip_runtime.h>
#include <hip/hip_bf16.h>
#include <math.h>

typedef __bf16 bf16x8 __attribute__((ext_vector_type(8)));
typedef float f32x4 __attribute__((ext_vector_type(4)));
typedef float f32x2 __attribute__((ext_vector_type(2)));
typedef unsigned short ushort8 __attribute__((ext_vector_type(8)));

static __device__ __forceinline__ unsigned short f2bf(float f) {
    union { float f; unsigned u; } c; c.f = f;
    unsigned r = c.u + 0x7FFFu + ((c.u >> 16) & 1u);   // RNE
    return (unsigned short)(r >> 16);
}

static __device__ __forceinline__ void gload_lds16(
    const unsigned short* g, unsigned short* l)
{
    __builtin_amdgcn_global_load_lds(
        (const __attribute__((address_space(1))) void*)g,
        (__attribute__((address_space(3))) void*)l, 16, 0, 0);
}

// ---------------------------------------------------------------------------
// Weight pre-conversion (fp32 -> bf16, concat [Wo;Wa], [bo;ba]) fused with
// the query-bucket histogram (16 buckets = batch x y-band).
__global__ __launch_bounds__(256) void convert_weights_hist(
    const float* __restrict__ Wv, const float* __restrict__ Wo,
    const float* __restrict__ Wa, const float* __restrict__ Wout,
    const float* __restrict__ bo, const float* __restrict__ ba,
    unsigned short* __restrict__ Wv_b, unsigned short* __restrict__ Woa_b,
    unsigned short* __restrict__ Wout_b, float* __restrict__ boa,
    const float* __restrict__ priors, int* __restrict__ counts,
    int BQ, int Nq)
{
    __shared__ int cnt[16];
    if (threadIdx.x < 16) cnt[threadIdx.x] = 0;
    __syncthreads();

    int gid = blockIdx.x * blockDim.x + threadIdx.x;
    int stride = gridDim.x * blockDim.x;
    for (int i = gid; i < 163840; i += stride) {
        if (i < 65536)       Wv_b[i] = f2bf(Wv[i]);
        else if (i < 90112)  Woa_b[i - 65536] = f2bf(Wo[i - 65536]);
        else if (i < 98304)  Woa_b[i - 65536] = f2bf(Wa[i - 90112]);
        else                 Wout_b[i - 98304] = f2bf(Wout[i - 98304]);
    }
    if (gid < 96)       boa[gid] = bo[gid];
    else if (gid < 128) boa[gid] = ba[gid - 96];

    for (int q = gid; q < BQ; q += stride) {
        int b = q / Nq;
        float py = priors[(size_t)q * 2 + 1];
        int band = min(7, max(0, (int)(py * 8.0f)));
        atomicAdd(&cnt[b * 8 + band], 1);
    }
    __syncthreads();
    if (threadIdx.x < 16 && cnt[threadIdx.x] > 0)
        atomicAdd(&counts[threadIdx.x], cnt[threadIdx.x]);
}

// Scatter query ids into bucket-sorted order. Each block computes the 16-way
// exclusive scan of the (completed) global counts locally — no scan kernel.
__global__ __launch_bounds__(256) void bucket_scatter(
    const float* __restrict__ priors, const int* __restrict__ counts,
    int* __restrict__ cursors, int* __restrict__ qidx, int BQ, int Nq)
{
    __shared__ int lcnt[16];
    __shared__ int lbase[16];
    const int tid = threadIdx.x;
    if (tid < 16) lcnt[tid] = 0;
    __syncthreads();
    int q = blockIdx.x * 256 + tid;
    int mybucket = 0, myslot = 0;
    bool valid = q < BQ;
    if (valid) {
        int b = q / Nq;
        float py = priors[(size_t)q * 2 + 1];
        int band = min(7, max(0, (int)(py * 8.0f)));
        mybucket = b * 8 + band;
        myslot = atomicAdd(&lcnt[mybucket], 1);
    }
    __syncthreads();
    if (tid < 16) {
        int base = 0;
        #pragma unroll
        for (int i = 0; i < 16; ++i) base += (i < tid) ? counts[i] : 0;
        lbase[tid] = base + atomicAdd(&cursors[tid], lcnt[tid]);
    }
    __syncthreads();
    if (valid) qidx[lbase[mybucket] + myslot] = q;
}

// ---------------------------------------------------------------------------
// C[M,N] = A[M,K] @ W^T + bias  via mfma_f32_16x16x32_bf16.
// W is bf16 [N][K] row-major, staged via global_load_lds (16B) into a linear
// LDS tile with XOR-swizzled storage (swizzle applied on the per-lane GLOBAL
// source address + the same XOR on ds_read — bank-conflict-free, m201).
// A: bf16 -> same async path; fp32 -> in-register convert to padded LDS.
// BM=64; BN = WN*64; block = WN waves, each wave computes 64x64.
// OUT_MODE: 0 = fp32 row-major [M,N]; 1 = bf16 row-major [M,N];
//           2 = bf16 head-major val layout [B=2, H=8, NsPB, 32].
template<int WN, bool A_BF16, int OUT_MODE>
__global__ __launch_bounds__(WN * 64) void gemm_mfma(
    const void* __restrict__ Av, const unsigned short* __restrict__ W,
    const float* __restrict__ bias, void* __restrict__ Cv,
    int M, int N, int K, int NsPB)
{
    constexpr int BM = 64;
    constexpr int BN = WN * 64;
    constexpr int BK = 64;
    constexpr int NTHR = WN * 64;
    constexpr int LDP = 72;                 // padded row stride (fp32-A path)
    constexpr int ASZ = A_BF16 ? (BM * 64) : (BM * LDP);

    __shared__ __align__(16) unsigned short As[ASZ];
    __shared__ __align__(16) unsigned short Bs[BN * 64];

    const int bm  = blockIdx.x * BM;
    const int bn  = blockIdx.y * BN;
    const int tid = threadIdx.x;
    const int wid = tid >> 6;
    const int lane = tid & 63;
    const int lr = lane & 15;               // col-in-fragment
    const int lg = lane >> 4;               // 0..3
    const int lrow = lane >> 3;             // 0..7 (row within 8-row chunk)
    const int lc16 = (lane & 7) ^ (lrow & 7); // pre-swizzled source col16

    f32x4 acc[4][4];
    #pragma unroll
    for (int mi = 0; mi < 4; ++mi)
        #pragma unroll
        for (int ni = 0; ni < 4; ++ni)
            acc[mi][ni] = (f32x4){0.f, 0.f, 0.f, 0.f};

    for (int kt = 0; kt < K; kt += BK) {
        // ---- B tile: async global->LDS, swizzled-source, linear dest
        #pragma unroll
        for (int c = wid; c < BN / 8; c += WN) {
            const unsigned short* g =
                W + (size_t)(bn + c * 8 + lrow) * K + kt + lc16 * 8;
            gload_lds16(g, Bs + c * 512);
        }
        // ---- A tile
        if (A_BF16) {
            const unsigned short* A = (const unsigned short*)Av;
            #pragma unroll
            for (int c = wid; c < BM / 8; c += WN) {
                const unsigned short* g =
                    A + (size_t)(bm + c * 8 + lrow) * K + kt + lc16 * 8;
                gload_lds16(g, As + c * 512);
            }
        } else {
            const float* A = (const float*)Av;
            #pragma unroll
            for (int u = tid; u < BM * 8; u += NTHR) {
                int r = u >> 3, kb = u & 7;
                const float* src = A + (size_t)(bm + r) * K + kt + kb * 8;
                float4 f0 = *(const float4*)(src);
                float4 f1 = *(const float4*)(src + 4);
                ushort8 v;
                v[0] = f2bf(f0.x); v[1] = f2bf(f0.y);
                v[2] = f2bf(f0.z); v[3] = f2bf(f0.w);
                v[4] = f2bf(f1.x); v[5] = f2bf(f1.y);
                v[6] = f2bf(f1.z); v[7] = f2bf(f1.w);
                *(ushort8*)(As + r * LDP + kb * 8) = v;
            }
        }
        __syncthreads();   // drains vmcnt (gload_lds) + lgkmcnt

        #pragma unroll
        for (int kk = 0; kk < 2; ++kk) {
            bf16x8 fa[4], fb[4];
            #pragma unroll
            for (int mi = 0; mi < 4; ++mi) {
                if (A_BF16) {
                    int row = mi * 16 + lr;
                    fa[mi] = *(const bf16x8*)(As + row * 64 +
                                              ((kk * 4 + lg) ^ (lr & 7)) * 8);
                } else {
                    fa[mi] = *(const bf16x8*)(As + (mi * 16 + lr) * LDP +
                                              kk * 32 + lg * 8);
                }
            }
            #pragma unroll
            for (int ni = 0; ni < 4; ++ni) {
                int row = wid * 64 + ni * 16 + lr;
                fb[ni] = *(const bf16x8*)(Bs + row * 64 +
                                          ((kk * 4 + lg) ^ (lr & 7)) * 8);
            }
            #pragma unroll
            for (int mi = 0; mi < 4; ++mi)
                #pragma unroll
                for (int ni = 0; ni < 4; ++ni)
                    acc[mi][ni] = __builtin_amdgcn_mfma_f32_16x16x32_bf16(
                        fa[mi], fb[ni], acc[mi][ni], 0, 0, 0);
        }
        __syncthreads();
    }

    // epilogue: C/D layout col = lane&15, row = (lane>>4)*4 + reg  [m89]
    if (OUT_MODE == 2) {
        const int b = bm / NsPB;            // block never straddles batch
        const int ns_base = bm - b * NsPB;
        #pragma unroll
        for (int ni = 0; ni < 4; ++ni) {
            int col = wid * 64 + ni * 16 + lr;        // bn == 0
            int h   = col >> 5;
            int ch  = col & 31;
            float bv = bias[col];
            unsigned short* dst = (unsigned short*)Cv +
                (size_t)(b * 8 + h) * NsPB * 32 + ch;
            #pragma unroll
            for (int mi = 0; mi < 4; ++mi) {
                #pragma unroll
                for (int r = 0; r < 4; ++r) {
                    int ns = ns_base + mi * 16 + lg * 4 + r;
                    dst[(size_t)ns * 32] = f2bf(acc[mi][ni][r] + bv);
                }
            }
        }
    } else {
        #pragma unroll
        for (int ni = 0; ni < 4; ++ni) {
            int col = bn + wid * 64 + ni * 16 + lr;
            float bv = bias[col];
            #pragma unroll
            for (int mi = 0; mi < 4; ++mi) {
                #pragma unroll
                for (int r = 0; r < 4; ++r) {
                    int row = bm + mi * 16 + lg * 4 + r;
                    if (OUT_MODE == 1) {
                        ((unsigned short*)Cv)[(size_t)row * N + col] =
                            f2bf(acc[mi][ni][r] + bv);
                    } else {
                        ((float*)Cv)[(size_t)row * N + col] = acc[mi][ni][r] + bv;
                    }
                }
            }
        }
    }
}

// ---------------------------------------------------------------------------
// Per-query fused sampling, one query per 256-thread block.
// Prologue (wave 0, lane=(hp,sl)): softmax, position math; emits 4 row-pair
// records per hp: {rowbase, pack(x0,Ws), w_x0, w_x1} into LDS [32][20]
// (b128-broadcast-friendly, conflict-free reads).
// Gather: thread (hp,d16): 8 lanes cover one 128B x-corner PAIR per row ->
// 4 unconditional 16B loads/thread, halved line-touches vs per-corner rows.
// Reduction entirely in-wave: x-group bit2, p bits 3-4 -> shfl_xor(4/8/16).
// No second barrier, no LDS reduce.
__global__ __launch_bounds__(256) void msda_sample_kernel(
    const float* __restrict__ C1,        // [BQ,128]: 96 offs + 32 attn logits
    const float* __restrict__ priors,    // [BQ,2]
    const unsigned short* __restrict__ val, // [B,8,Ns,32] bf16
    const int*   __restrict__ map_hw,    // [4][2] (H,W)
    const int*   __restrict__ map_offs,  // [4]
    const int*   __restrict__ map_ids,   // [B,Ns]
    const int*   __restrict__ qidx,      // [BQ] bucket-sorted query ids
    unsigned short* __restrict__ out,    // [BQ,256] bf16
    int Nq, int Ns)
{
    // XCD-chunked swizzle (nwg % 8 == 0): contiguous chunk per XCD
    const int swz = (blockIdx.x & 7) * (gridDim.x >> 3) + (blockIdx.x >> 3);
    const int bq  = qidx[swz];
    const int t   = threadIdx.x;
    const int b   = bq / Nq;
    const int q   = bq - b * Nq;

    __shared__ __align__(16) float s_row[32 * 20];  // [hp][j*4 + {rb,xw,w0,w1}]

    if (t < 64) {
        const int hp = t >> 1;          // 0..31 = h*4+p
        const int sl = t & 1;           // level slot
        const float* sc = C1 + (size_t)bq * 128;
        float o0 = sc[hp * 3 + 0];
        float o1 = sc[hp * 3 + 1];
        float o2 = sc[hp * 3 + 2];
        float logit = sc[96 + hp];

        // softmax over the 4 points of this head: p lives in lane bits 1..2
        float m = logit;
        m = fmaxf(m, __shfl_xor(m, 2));
        m = fmaxf(m, __shfl_xor(m, 4));
        float e = expf(logit - m);
        float s = e;
        s += __shfl_xor(s, 2);
        s += __shfl_xor(s, 4);
        float attnw = e / s;

        int lid = map_ids[(size_t)b * Ns + q];
        float px = priors[(size_t)bq * 2 + 0];
        float py = priors[(size_t)bq * 2 + 1];
        int Hq = map_hw[lid * 2 + 0];
        int Wq = map_hw[lid * 2 + 1];
        float x = px + o0 / (float)Wq;
        float y = py + o1 / (float)Hq;

        float lvl_f = (float)lid + tanhf(o2);
        float l0f = floorf(lvl_f);
        int   l0  = (int)l0f;
        float wz  = lvl_f - l0f;

        const int   lv = l0 + sl;
        const float wl = (sl ? wz : (1.0f - wz)) * attnw;

        float w0[2] = {0.f, 0.f}, w1[2] = {0.f, 0.f};
        int   rb[2] = {0, 0};
        int   xw[2];
        xw[0] = xw[1] = (1 << 16) | 512;      // Ws=1, x0=0 (safe dummy)
        if (lv >= 0 && lv < 4) {
            int Hs  = map_hw[lv * 2 + 0];
            int Ws  = map_hw[lv * 2 + 1];
            int off = map_offs[lv];
            float xf = x * (float)Ws - 0.5f;
            float yf = y * (float)Hs - 0.5f;
            float x0f = floorf(xf), y0f = floorf(yf);
            int   x0  = (int)x0f,  y0  = (int)y0f;
            float dx = xf - x0f, dy = yf - y0f;
            int   xp = (Ws << 16) | ((x0 + 512) & 0xffff);
            #pragma unroll
            for (int yc = 0; yc < 2; ++yc) {
                int  yi = y0 + yc;
                bool vy = (yi >= 0) && (yi < Hs);
                int  yic = min(max(yi, 0), Hs - 1);
                float wy = (yc ? dy : (1.0f - dy)) * wl * (vy ? 1.0f : 0.0f);
                rb[yc] = off + yic * Ws;
                xw[yc] = xp;
                w0[yc] = wy * (1.0f - dx);
                w1[yc] = wy * dx;
            }
        }
        #pragma unroll
        for (int yc = 0; yc < 2; ++yc) {
            int j = sl * 2 + yc;
            f32x4 rec;
            rec[0] = __int_as_float(rb[yc]);
            rec[1] = __int_as_float(xw[yc]);
            rec[2] = w0[yc];
            rec[3] = w1[yc];
            *(f32x4*)(s_row + hp * 20 + j * 4) = rec;
        }
    }
    __syncthreads();

    const int hp   = t >> 3;         // 0..31
    const int d16  = t & 7;          // 0..7 within the 128B row-pair
    const int xg   = (t >> 2) & 1;   // x-corner group
    const int boff = (t & 3) * 16;   // byte offset within 64B row

    const char* vbase = (const char*)(val + (size_t)(b * 8 + (hp >> 2)) * Ns * 32);
    f32x2 acc2[4];
    #pragma unroll
    for (int k = 0; k < 4; ++k) acc2[k] = (f32x2){0.f, 0.f};

    #pragma unroll
    for (int j = 0; j < 4; ++j) {
        f32x4 rec = *(const f32x4*)(s_row + hp * 20 + j * 4);
        int   rb = __float_as_int(rec[0]);
        int   xw = __float_as_int(rec[1]);
        float w  = xg ? rec[3] : rec[2];
        int   Ws = xw >> 16;
        int   xi = (xw & 0xffff) - 512 + xg;
        bool  in = (xi >= 0) && (xi < Ws);
        int   xic = min(max(xi, 0), Ws - 1);
        w = in ? w : 0.0f;
        uint4 u = *(const uint4*)(vbase + (size_t)(unsigned)((rb + xic) << 6) + boff);
        f32x2 w2 = {w, w};
        unsigned ua[4] = {u.x, u.y, u.z, u.w};
        #pragma unroll
        for (int k = 0; k < 4; ++k) {
            union { unsigned u; float f; } lo, hi;
            lo.u = ua[k] << 16;
            hi.u = ua[k] & 0xffff0000u;
            f32x2 v2 = {lo.f, hi.f};
            acc2[k] += w2 * v2;          // v_pk_fma_f32
        }
    }

    // in-wave reduction over xg (bit 2) and p (bits 3,4)
    #pragma unroll
    for (int k = 0; k < 4; ++k) {
        acc2[k][0] += __shfl_xor(acc2[k][0], 4);
        acc2[k][1] += __shfl_xor(acc2[k][1], 4);
        acc2[k][0] += __shfl_xor(acc2[k][0], 8);
        acc2[k][1] += __shfl_xor(acc2[k][1], 8);
        acc2[k][0] += __shfl_xor(acc2[k][0], 16);
        acc2[k][1] += __shfl_xor(acc2[k][1], 16);
    }

    if ((t & 28) == 0) {            // p==0, xg==0 lanes: 32 writers
        const int h  = t >> 5;      // 0..7
        const int d8 = t & 3;       // 0..3
        ushort8 o;
        #pragma unroll
        for (int k = 0; k < 4; ++k) {
            o[2 * k]     = f2bf(acc2[k][0]);
            o[2 * k + 1] = f2bf(acc2[k][1]);
        }
        *(ushort8*)(out + (size_t)bq * 256 + h * 32 + d8 * 8) = o;
    }
}

extern "C" void kernel_launch(void* const* d_in, const int* in_sizes, int n_in,
                              void* d_out, int out_size, void* d_ws, size_t ws_size,
                              hipStream_t stream) {
    const float* in_feats      = (const float*)d_in[0];
    const float* sample_priors = (const float*)d_in[1];
    const float* sample_feats  = (const float*)d_in[2];
    const int*   map_hw        = (const int*)d_in[3];
    const int*   map_offs      = (const int*)d_in[4];
    const int*   map_ids       = (const int*)d_in[5];
    const float* Wo            = (const float*)d_in[6];
    const float* bo            = (const float*)d_in[7];
    const float* Wa            = (const float*)d_in[8];
    const float* ba            = (const float*)d_in[9];
    const float* Wv            = (const float*)d_in[10];
    const float* bv            = (const float*)d_in[11];
    const float* Wout          = (const float*)d_in[12];
    const float* bout          = (const float*)d_in[13];
    float* out = (float*)d_out;

    const int B = 2, Nq = 21760, Din = 256;
    const int Ns = in_sizes[2] / (B * Din);   // 21760
    const int BQ = B * Nq;                    // 43520

    // Workspace layout
    unsigned short* val = (unsigned short*)d_out;   // [B,8,Ns,32] bf16 (dead before K4)
    float* C1 = (float*)d_ws;                       // [BQ,128] f32
    unsigned short* af = (unsigned short*)((char*)d_ws + (size_t)BQ * 128 * 4); // [BQ,256] bf16
    char* wbase = (char*)d_ws + (size_t)BQ * 128 * 4 + (size_t)BQ * 256 * 2;
    unsigned short* Wv_b   = (unsigned short*)wbase;          // 65536
    unsigned short* Woa_b  = Wv_b + 65536;                    // 32768 ([Wo;Wa])
    unsigned short* Wout_b = Woa_b + 32768;                   // 65536
    float* boa = (float*)(Wout_b + 65536);                    // 128 ([bo;ba])
    int* bws  = (int*)(boa + 128);                            // 32: counts+cursors
    int* qidx = bws + 32;                                     // [BQ]

    // zero bucket counters (counts[16] + cursors[16])
    hipMemsetAsync(bws, 0, 128, stream);

    // K0: weight conversion + bucket histogram (fused, tiny)
    convert_weights_hist<<<dim3(160), dim3(256), 0, stream>>>(
        Wv, Wo, Wa, Wout, bo, ba, Wv_b, Woa_b, Wout_b, boa,
        sample_priors, bws, BQ, Nq);

    // K0b: scatter query ids into bucket order (local scan per block)
    bucket_scatter<<<dim3((BQ + 255) / 256), dim3(256), 0, stream>>>(
        sample_priors, bws, bws + 16, qidx, BQ, Nq);

    // K1: val = bf16(sample_feats @ Wv^T + bv), head-major layout
    gemm_mfma<4, false, 2><<<dim3(BQ / 64, 1), dim3(256), 0, stream>>>(
        sample_feats, Wv_b, bv, val, B * Ns, 256, Din, Ns);

    // K2: C1 = in_feats @ [Wo;Wa]^T + [bo;ba]   [43520,256]x[256,128]
    gemm_mfma<2, false, 0><<<dim3(BQ / 64, 1), dim3(128), 0, stream>>>(
        in_feats, Woa_b, boa, C1, BQ, 128, Din, Ns);

    // K3: fused softmax + trilinear sampling -> attn_feats (bf16)
    msda_sample_kernel<<<dim3(BQ), dim3(256), 0, stream>>>(
        C1, sample_priors, val, map_hw, map_offs, map_ids, qidx, af, Nq, Ns);

    // K4: out = attn_feats @ Wout^T + bout   [43520,256]x[256,256]
    gemm_mfma<4, true, 0><<<dim3(BQ / 64, 1), dim3(256), 0, stream>>>(
        af, Wout_b, bout, out, BQ, 256, Din, Ns);
}

// Round 10
// 108.362 us; speedup vs baseline: 1.3189x; 1.3189x over previous
//
#include <hip/hip_runtime.h>
#include <hip/hip_bf16.h>
#include <math.h>

typedef __bf16 bf16x8 __attribute__((ext_vector_type(8)));
typedef float f32x4 __attribute__((ext_vector_type(4)));
typedef float f32x2 __attribute__((ext_vector_type(2)));
typedef unsigned short ushort8 __attribute__((ext_vector_type(8)));

static __device__ __forceinline__ unsigned short f2bf(float f) {
    union { float f; unsigned u; } c; c.f = f;
    unsigned r = c.u + 0x7FFFu + ((c.u >> 16) & 1u);   // RNE
    return (unsigned short)(r >> 16);
}

static __device__ __forceinline__ void gload_lds16(
    const unsigned short* g, unsigned short* l)
{
    __builtin_amdgcn_global_load_lds(
        (const __attribute__((address_space(1))) void*)g,
        (__attribute__((address_space(3))) void*)l, 16, 0, 0);
}

// ---------------------------------------------------------------------------
// Weight pre-conversion (fp32 -> bf16, concat [Wo;Wa], [bo;ba]) fused with
// the query-bucket histogram (16 buckets = batch x y-band).
__global__ __launch_bounds__(256) void convert_weights_hist(
    const float* __restrict__ Wv, const float* __restrict__ Wo,
    const float* __restrict__ Wa, const float* __restrict__ Wout,
    const float* __restrict__ bo, const float* __restrict__ ba,
    unsigned short* __restrict__ Wv_b, unsigned short* __restrict__ Woa_b,
    unsigned short* __restrict__ Wout_b, float* __restrict__ boa,
    const float* __restrict__ priors, int* __restrict__ counts,
    int BQ, int Nq)
{
    __shared__ int cnt[16];
    if (threadIdx.x < 16) cnt[threadIdx.x] = 0;
    __syncthreads();

    int gid = blockIdx.x * blockDim.x + threadIdx.x;
    int stride = gridDim.x * blockDim.x;
    for (int i = gid; i < 163840; i += stride) {
        if (i < 65536)       Wv_b[i] = f2bf(Wv[i]);
        else if (i < 90112)  Woa_b[i - 65536] = f2bf(Wo[i - 65536]);
        else if (i < 98304)  Woa_b[i - 65536] = f2bf(Wa[i - 90112]);
        else                 Wout_b[i - 98304] = f2bf(Wout[i - 98304]);
    }
    if (gid < 96)       boa[gid] = bo[gid];
    else if (gid < 128) boa[gid] = ba[gid - 96];

    for (int q = gid; q < BQ; q += stride) {
        int b = q / Nq;
        float py = priors[(size_t)q * 2 + 1];
        int band = min(7, max(0, (int)(py * 8.0f)));
        atomicAdd(&cnt[b * 8 + band], 1);
    }
    __syncthreads();
    if (threadIdx.x < 16 && cnt[threadIdx.x] > 0)
        atomicAdd(&counts[threadIdx.x], cnt[threadIdx.x]);
}

// Scatter query ids into bucket-sorted order. Each block computes the 16-way
// exclusive scan of the (completed) global counts locally — no scan kernel.
__global__ __launch_bounds__(256) void bucket_scatter(
    const float* __restrict__ priors, const int* __restrict__ counts,
    int* __restrict__ cursors, int* __restrict__ qidx, int BQ, int Nq)
{
    __shared__ int lcnt[16];
    __shared__ int lbase[16];
    const int tid = threadIdx.x;
    if (tid < 16) lcnt[tid] = 0;
    __syncthreads();
    int q = blockIdx.x * 256 + tid;
    int mybucket = 0, myslot = 0;
    bool valid = q < BQ;
    if (valid) {
        int b = q / Nq;
        float py = priors[(size_t)q * 2 + 1];
        int band = min(7, max(0, (int)(py * 8.0f)));
        mybucket = b * 8 + band;
        myslot = atomicAdd(&lcnt[mybucket], 1);
    }
    __syncthreads();
    if (tid < 16) {
        int base = 0;
        #pragma unroll
        for (int i = 0; i < 16; ++i) base += (i < tid) ? counts[i] : 0;
        lbase[tid] = base + atomicAdd(&cursors[tid], lcnt[tid]);
    }
    __syncthreads();
    if (valid) qidx[lbase[mybucket] + myslot] = q;
}

// ---------------------------------------------------------------------------
// C[M,N] = A[M,K] @ W^T + bias  via mfma_f32_16x16x32_bf16.
// W is bf16 [N][K] row-major, staged via global_load_lds (16B) into a linear
// LDS tile with XOR-swizzled storage (swizzle applied on the per-lane GLOBAL
// source address + the same XOR on ds_read — bank-conflict-free, m201).
// A: bf16 -> same async path; fp32 -> in-register convert to padded LDS.
// BM=64; BN = WN*64; block = WN waves, each wave computes 64x64.
// OUT_MODE: 0 = fp32 row-major [M,N]; 1 = bf16 row-major [M,N];
//           2 = bf16 head-major val layout [B=2, H=8, NsPB, 32].
template<int WN, bool A_BF16, int OUT_MODE>
__global__ __launch_bounds__(WN * 64) void gemm_mfma(
    const void* __restrict__ Av, const unsigned short* __restrict__ W,
    const float* __restrict__ bias, void* __restrict__ Cv,
    int M, int N, int K, int NsPB)
{
    constexpr int BM = 64;
    constexpr int BN = WN * 64;
    constexpr int BK = 64;
    constexpr int NTHR = WN * 64;
    constexpr int LDP = 72;                 // padded row stride (fp32-A path)
    constexpr int ASZ = A_BF16 ? (BM * 64) : (BM * LDP);

    __shared__ __align__(16) unsigned short As[ASZ];
    __shared__ __align__(16) unsigned short Bs[BN * 64];

    const int bm  = blockIdx.x * BM;
    const int bn  = blockIdx.y * BN;
    const int tid = threadIdx.x;
    const int wid = tid >> 6;
    const int lane = tid & 63;
    const int lr = lane & 15;               // col-in-fragment
    const int lg = lane >> 4;               // 0..3
    const int lrow = lane >> 3;             // 0..7 (row within 8-row chunk)
    const int lc16 = (lane & 7) ^ (lrow & 7); // pre-swizzled source col16

    f32x4 acc[4][4];
    #pragma unroll
    for (int mi = 0; mi < 4; ++mi)
        #pragma unroll
        for (int ni = 0; ni < 4; ++ni)
            acc[mi][ni] = (f32x4){0.f, 0.f, 0.f, 0.f};

    for (int kt = 0; kt < K; kt += BK) {
        // ---- B tile: async global->LDS, swizzled-source, linear dest
        #pragma unroll
        for (int c = wid; c < BN / 8; c += WN) {
            const unsigned short* g =
                W + (size_t)(bn + c * 8 + lrow) * K + kt + lc16 * 8;
            gload_lds16(g, Bs + c * 512);
        }
        // ---- A tile
        if (A_BF16) {
            const unsigned short* A = (const unsigned short*)Av;
            #pragma unroll
            for (int c = wid; c < BM / 8; c += WN) {
                const unsigned short* g =
                    A + (size_t)(bm + c * 8 + lrow) * K + kt + lc16 * 8;
                gload_lds16(g, As + c * 512);
            }
        } else {
            const float* A = (const float*)Av;
            #pragma unroll
            for (int u = tid; u < BM * 8; u += NTHR) {
                int r = u >> 3, kb = u & 7;
                const float* src = A + (size_t)(bm + r) * K + kt + kb * 8;
                float4 f0 = *(const float4*)(src);
                float4 f1 = *(const float4*)(src + 4);
                ushort8 v;
                v[0] = f2bf(f0.x); v[1] = f2bf(f0.y);
                v[2] = f2bf(f0.z); v[3] = f2bf(f0.w);
                v[4] = f2bf(f1.x); v[5] = f2bf(f1.y);
                v[6] = f2bf(f1.z); v[7] = f2bf(f1.w);
                *(ushort8*)(As + r * LDP + kb * 8) = v;
            }
        }
        __syncthreads();   // drains vmcnt (gload_lds) + lgkmcnt

        #pragma unroll
        for (int kk = 0; kk < 2; ++kk) {
            bf16x8 fa[4], fb[4];
            #pragma unroll
            for (int mi = 0; mi < 4; ++mi) {
                if (A_BF16) {
                    int row = mi * 16 + lr;
                    fa[mi] = *(const bf16x8*)(As + row * 64 +
                                              ((kk * 4 + lg) ^ (lr & 7)) * 8);
                } else {
                    fa[mi] = *(const bf16x8*)(As + (mi * 16 + lr) * LDP +
                                              kk * 32 + lg * 8);
                }
            }
            #pragma unroll
            for (int ni = 0; ni < 4; ++ni) {
                int row = wid * 64 + ni * 16 + lr;
                fb[ni] = *(const bf16x8*)(Bs + row * 64 +
                                          ((kk * 4 + lg) ^ (lr & 7)) * 8);
            }
            #pragma unroll
            for (int mi = 0; mi < 4; ++mi)
                #pragma unroll
                for (int ni = 0; ni < 4; ++ni)
                    acc[mi][ni] = __builtin_amdgcn_mfma_f32_16x16x32_bf16(
                        fa[mi], fb[ni], acc[mi][ni], 0, 0, 0);
        }
        __syncthreads();
    }

    // epilogue: C/D layout col = lane&15, row = (lane>>4)*4 + reg  [m89]
    if (OUT_MODE == 2) {
        const int b = bm / NsPB;            // block never straddles batch
        const int ns_base = bm - b * NsPB;
        #pragma unroll
        for (int ni = 0; ni < 4; ++ni) {
            int col = wid * 64 + ni * 16 + lr;        // bn == 0
            int h   = col >> 5;
            int ch  = col & 31;
            float bv = bias[col];
            unsigned short* dst = (unsigned short*)Cv +
                (size_t)(b * 8 + h) * NsPB * 32 + ch;
            #pragma unroll
            for (int mi = 0; mi < 4; ++mi) {
                #pragma unroll
                for (int r = 0; r < 4; ++r) {
                    int ns = ns_base + mi * 16 + lg * 4 + r;
                    dst[(size_t)ns * 32] = f2bf(acc[mi][ni][r] + bv);
                }
            }
        }
    } else {
        #pragma unroll
        for (int ni = 0; ni < 4; ++ni) {
            int col = bn + wid * 64 + ni * 16 + lr;
            float bv = bias[col];
            #pragma unroll
            for (int mi = 0; mi < 4; ++mi) {
                #pragma unroll
                for (int r = 0; r < 4; ++r) {
                    int row = bm + mi * 16 + lg * 4 + r;
                    if (OUT_MODE == 1) {
                        ((unsigned short*)Cv)[(size_t)row * N + col] =
                            f2bf(acc[mi][ni][r] + bv);
                    } else {
                        ((float*)Cv)[(size_t)row * N + col] = acc[mi][ni][r] + bv;
                    }
                }
            }
        }
    }
}

// ---------------------------------------------------------------------------
// Per-query fused sampling — ONE QUERY PER WAVE, fully wave-autonomous
// (no __syncthreads). Prologue: all 64 lanes = (hp, sl) compute softmax +
// positions; each lane writes its 4-corner record (w4, i4) as two b128s into
// a per-wave 2KB LDS slice, plane-interleaved [plane][hp*16B] so reads and
// writes are at worst 2-way bank-conflicted (free).
// Gather: lane = (h, d8, p2) accumulates TWO p-values (16 global 16B loads
// in flight), reduction is a single shfl_xor(1). DS-pipe traffic per query
// roughly halves vs the 2-wave R8 layout, and both barriers disappear.
__global__ __launch_bounds__(256) void msda_sample_kernel(
    const float* __restrict__ C1,        // [BQ,128]: 96 offs + 32 attn logits
    const float* __restrict__ priors,    // [BQ,2]
    const unsigned short* __restrict__ val, // [B,8,Ns,32] bf16
    const int*   __restrict__ map_hw,    // [4][2] (H,W)
    const int*   __restrict__ map_offs,  // [4]
    const int*   __restrict__ map_ids,   // [B,Ns]
    const int*   __restrict__ qidx,      // [BQ] bucket-sorted query ids
    unsigned short* __restrict__ out,    // [BQ,256] bf16
    int Nq, int Ns)
{
    // XCD-chunked swizzle (nwg % 8 == 0): contiguous chunk per XCD
    const int swz  = (blockIdx.x & 7) * (gridDim.x >> 3) + (blockIdx.x >> 3);
    const int wvi  = threadIdx.x >> 6;       // wave index = query slot
    const int lane = threadIdx.x & 63;
    const int bq   = qidx[swz * 4 + wvi];
    const int b    = bq / Nq;
    const int q    = bq - b * Nq;

    // [wave][plane][128 floats]: plane 0/1 = w4 (sl=0/1), plane 2/3 = i4
    __shared__ __align__(16) float s_rec[4][4][128];

    // ---- prologue: every lane active, lane = (hp, sl)
    {
        const int hp = lane >> 1;
        const int sl = lane & 1;
        const float* sc = C1 + (size_t)bq * 128;
        float o0 = sc[hp * 3 + 0];
        float o1 = sc[hp * 3 + 1];
        float o2 = sc[hp * 3 + 2];
        float logit = sc[96 + hp];

        // softmax over the 4 points of this head: p lives in lane bits 1..2
        float m = logit;
        m = fmaxf(m, __shfl_xor(m, 2));
        m = fmaxf(m, __shfl_xor(m, 4));
        float e = expf(logit - m);
        float s = e;
        s += __shfl_xor(s, 2);
        s += __shfl_xor(s, 4);
        float attnw = e / s;

        int lid = map_ids[(size_t)b * Ns + q];
        float px = priors[(size_t)bq * 2 + 0];
        float py = priors[(size_t)bq * 2 + 1];
        int Hq = map_hw[lid * 2 + 0];
        int Wq = map_hw[lid * 2 + 1];
        float x = px + o0 / (float)Wq;
        float y = py + o1 / (float)Hq;

        float lvl_f = (float)lid + tanhf(o2);
        float l0f = floorf(lvl_f);
        int   l0  = (int)l0f;
        float wz  = lvl_f - l0f;

        const int   lv = l0 + sl;
        const float wl = sl ? wz : (1.0f - wz);
        float w4[4];
        int   i4[4];
        if (lv >= 0 && lv < 4) {
            int Hs  = map_hw[lv * 2 + 0];
            int Ws  = map_hw[lv * 2 + 1];
            int off = map_offs[lv];
            float xf = x * (float)Ws - 0.5f;
            float yf = y * (float)Hs - 0.5f;
            float x0f = floorf(xf), y0f = floorf(yf);
            int   x0  = (int)x0f,  y0  = (int)y0f;
            float dx = xf - x0f, dy = yf - y0f;
            #pragma unroll
            for (int j = 0; j < 4; ++j) {
                int xi = x0 + (j & 1);
                int yi = y0 + (j >> 1);
                float w = ((j & 1) ? dx : 1.0f - dx) *
                          ((j >> 1) ? dy : 1.0f - dy);
                bool ok = (xi >= 0) && (xi < Ws) && (yi >= 0) && (yi < Hs);
                w4[j] = ok ? (w * wl * attnw) : 0.0f;
                i4[j] = ok ? ((off + yi * Ws + xi) << 6) : 0;  // BYTES
            }
        } else {
            #pragma unroll
            for (int j = 0; j < 4; ++j) { w4[j] = 0.0f; i4[j] = 0; }
        }
        f32x4 wrec = {w4[0], w4[1], w4[2], w4[3]};
        f32x4 irec = {__int_as_float(i4[0]), __int_as_float(i4[1]),
                      __int_as_float(i4[2]), __int_as_float(i4[3])};
        *(f32x4*)&s_rec[wvi][sl][hp * 4]     = wrec;
        *(f32x4*)&s_rec[wvi][2 + sl][hp * 4] = irec;
    }
    // same-wave LDS: ensure writes complete before reads; no barrier needed
    asm volatile("s_waitcnt lgkmcnt(0)" ::: "memory");

    // ---- gather: lane = (h, d8, p2)
    const int p2 = lane & 1;
    const int d8 = (lane >> 1) & 3;
    const int h  = lane >> 3;
    const char* vbase = (const char*)(val + (size_t)(b * 8 + h) * Ns * 32)
                        + d8 * 16;

    f32x2 acc2[4];
    #pragma unroll
    for (int k = 0; k < 4; ++k) acc2[k] = (f32x2){0.f, 0.f};

    #pragma unroll
    for (int pp = 0; pp < 2; ++pp) {
        const int hp = h * 4 + p2 + pp * 2;
        f32x4 wlo = *(const f32x4*)&s_rec[wvi][0][hp * 4];
        f32x4 whi = *(const f32x4*)&s_rec[wvi][1][hp * 4];
        f32x4 xlo = *(const f32x4*)&s_rec[wvi][2][hp * 4];
        f32x4 xhi = *(const f32x4*)&s_rec[wvi][3][hp * 4];

        uint4 u[8];
        #pragma unroll
        for (int j = 0; j < 4; ++j)
            u[j] = *(const uint4*)(vbase + __float_as_int(xlo[j]));
        #pragma unroll
        for (int j = 0; j < 4; ++j)
            u[4 + j] = *(const uint4*)(vbase + __float_as_int(xhi[j]));

        #pragma unroll
        for (int j = 0; j < 8; ++j) {
            float w = (j < 4) ? wlo[j] : whi[j - 4];
            f32x2 w2 = {w, w};
            unsigned ua[4] = {u[j].x, u[j].y, u[j].z, u[j].w};
            #pragma unroll
            for (int k = 0; k < 4; ++k) {
                union { unsigned u; float f; } lo, hi;
                lo.u = ua[k] << 16;
                hi.u = ua[k] & 0xffff0000u;
                f32x2 v2 = {lo.f, hi.f};
                acc2[k] += w2 * v2;          // v_pk_fma_f32
            }
        }
    }

    // reduce the p2 pair (lane bit 0)
    #pragma unroll
    for (int k = 0; k < 4; ++k) {
        acc2[k][0] += __shfl_xor(acc2[k][0], 1);
        acc2[k][1] += __shfl_xor(acc2[k][1], 1);
    }

    if (p2 == 0) {                   // 32 writers per wave
        ushort8 o;
        #pragma unroll
        for (int k = 0; k < 4; ++k) {
            o[2 * k]     = f2bf(acc2[k][0]);
            o[2 * k + 1] = f2bf(acc2[k][1]);
        }
        *(ushort8*)(out + (size_t)bq * 256 + h * 32 + d8 * 8) = o;
    }
}

extern "C" void kernel_launch(void* const* d_in, const int* in_sizes, int n_in,
                              void* d_out, int out_size, void* d_ws, size_t ws_size,
                              hipStream_t stream) {
    const float* in_feats      = (const float*)d_in[0];
    const float* sample_priors = (const float*)d_in[1];
    const float* sample_feats  = (const float*)d_in[2];
    const int*   map_hw        = (const int*)d_in[3];
    const int*   map_offs      = (const int*)d_in[4];
    const int*   map_ids       = (const int*)d_in[5];
    const float* Wo            = (const float*)d_in[6];
    const float* bo            = (const float*)d_in[7];
    const float* Wa            = (const float*)d_in[8];
    const float* ba            = (const float*)d_in[9];
    const float* Wv            = (const float*)d_in[10];
    const float* bv            = (const float*)d_in[11];
    const float* Wout          = (const float*)d_in[12];
    const float* bout          = (const float*)d_in[13];
    float* out = (float*)d_out;

    const int B = 2, Nq = 21760, Din = 256;
    const int Ns = in_sizes[2] / (B * Din);   // 21760
    const int BQ = B * Nq;                    // 43520

    // Workspace layout
    unsigned short* val = (unsigned short*)d_out;   // [B,8,Ns,32] bf16 (dead before K4)
    float* C1 = (float*)d_ws;                       // [BQ,128] f32
    unsigned short* af = (unsigned short*)((char*)d_ws + (size_t)BQ * 128 * 4); // [BQ,256] bf16
    char* wbase = (char*)d_ws + (size_t)BQ * 128 * 4 + (size_t)BQ * 256 * 2;
    unsigned short* Wv_b   = (unsigned short*)wbase;          // 65536
    unsigned short* Woa_b  = Wv_b + 65536;                    // 32768 ([Wo;Wa])
    unsigned short* Wout_b = Woa_b + 32768;                   // 65536
    float* boa = (float*)(Wout_b + 65536);                    // 128 ([bo;ba])
    int* bws  = (int*)(boa + 128);                            // 32: counts+cursors
    int* qidx = bws + 32;                                     // [BQ]

    // zero bucket counters (counts[16] + cursors[16])
    hipMemsetAsync(bws, 0, 128, stream);

    // K0: weight conversion + bucket histogram (fused, tiny)
    convert_weights_hist<<<dim3(160), dim3(256), 0, stream>>>(
        Wv, Wo, Wa, Wout, bo, ba, Wv_b, Woa_b, Wout_b, boa,
        sample_priors, bws, BQ, Nq);

    // K0b: scatter query ids into bucket order (local scan per block)
    bucket_scatter<<<dim3((BQ + 255) / 256), dim3(256), 0, stream>>>(
        sample_priors, bws, bws + 16, qidx, BQ, Nq);

    // K1: val = bf16(sample_feats @ Wv^T + bv), head-major layout
    gemm_mfma<4, false, 2><<<dim3(BQ / 64, 1), dim3(256), 0, stream>>>(
        sample_feats, Wv_b, bv, val, B * Ns, 256, Din, Ns);

    // K2: C1 = in_feats @ [Wo;Wa]^T + [bo;ba]   [43520,256]x[256,128]
    gemm_mfma<2, false, 0><<<dim3(BQ / 64, 1), dim3(128), 0, stream>>>(
        in_feats, Woa_b, boa, C1, BQ, 128, Din, Ns);

    // K3: fused softmax + trilinear sampling -> attn_feats (bf16)
    //     one query per wave, 4 queries per block
    msda_sample_kernel<<<dim3(BQ / 4), dim3(256), 0, stream>>>(
        C1, sample_priors, val, map_hw, map_offs, map_ids, qidx, af, Nq, Ns);

    // K4: out = attn_feats @ Wout^T + bout   [43520,256]x[256,256]
    gemm_mfma<4, true, 0><<<dim3(BQ / 64, 1), dim3(256), 0, stream>>>(
        af, Wout_b, bout, out, BQ, 256, Din, Ns);
}